// Round 3
// baseline (984.126 us; speedup 1.0000x reference)
//
#include <hip/hip_runtime.h>

// Problem constants (fixed by the reference file).
#define NAGENTS 2000000
#define GH 800000
#define GC 20000
#define GS 65000
#define GT (GH + GC + GS)   // 885000 total groups
#define TSTEPS 10
#define NXCD 8

// Fixed-point group-sum encoding, one uint64 per group:
//   bits [0,51)  : sum of round(transm * 2^44)   (exact to ~6e-12 per group)
//   bits [51,64) : member count
// Proven numerics -- do not touch.
#define FIXD   17592186044416.0          // 2^44
#define INVFIX (1.0 / 17592186044416.0)  // 2^-44
#define DELTA  3518437208883ULL          // round(0.2 * 2^44)
#define CUNIT  (1ULL << 51)
#define SMASK  (CUNIT - 1ULL)

// Packed per-agent state, one uint64:
//   bits [0,20)  : gh   (< 800000 < 2^20)
//   bits [20,35) : gc   (< 20000  < 2^15)
//   bits [35,52) : gs   (< 65000  < 2^17)
//   bit  63      : susceptible flag (setup guarantees susc in {1.0, 0.0})
#define SUSCBIT (1ULL << 63)

// ---------------------------------------------------------------------------
// init (replicated): pack agent state; scatter (count, fp sum) into the
// replica belonging to THIS block's XCD using workgroup-scope atomics.
// Workgroup-scope atomics execute at the XCD's L2 (TCC) -- atomic across all
// CUs of that XCD, which is exactly the set of writers of this replica.
// This keeps 6M RMWs off the fabric coherent point (the round-2 bottleneck).
// ---------------------------------------------------------------------------
__global__ void init_pack_repl_kernel(const float* __restrict__ transm_in,
                                      const float* __restrict__ susc_in,
                                      const int* __restrict__ gh,
                                      const int* __restrict__ gc,
                                      const int* __restrict__ gs,
                                      unsigned long long* __restrict__ repl,
                                      unsigned long long* __restrict__ packed,
                                      int n) {
    int i = blockIdx.x * blockDim.x + threadIdx.x;
    if (i >= n) return;

    unsigned xcd;
    asm volatile("s_getreg_b32 %0, hwreg(HW_REG_XCC_ID)" : "=s"(xcd));
    unsigned long long* myrep = repl + (size_t)(xcd & (NXCD - 1)) * GT;

    int a = __builtin_nontemporal_load(&gh[i]);
    int b = __builtin_nontemporal_load(&gc[i]);
    int c = __builtin_nontemporal_load(&gs[i]);
    float sv = __builtin_nontemporal_load(&susc_in[i]);
    float tv = __builtin_nontemporal_load(&transm_in[i]);

    unsigned long long w = (unsigned long long)(unsigned)a
                         | ((unsigned long long)(unsigned)b << 20)
                         | ((unsigned long long)(unsigned)c << 35)
                         | (sv != 0.0f ? SUSCBIT : 0ULL);
    __builtin_nontemporal_store(w, &packed[i]);

    unsigned long long e =
        (unsigned long long)((double)tv * FIXD + 0.5) + CUNIT;
    __hip_atomic_fetch_add(&myrep[a], e, __ATOMIC_RELAXED,
                           __HIP_MEMORY_SCOPE_WORKGROUP);
    __hip_atomic_fetch_add(&myrep[GH + b], e, __ATOMIC_RELAXED,
                           __HIP_MEMORY_SCOPE_WORKGROUP);
    __hip_atomic_fetch_add(&myrep[GH + GC + c], e, __ATOMIC_RELAXED,
                           __HIP_MEMORY_SCOPE_WORKGROUP);
}

// ---------------------------------------------------------------------------
// combine_from_repl (t=0 only): reduce the 8 replicas -> buf[g] (canonical,
// subsequently updated by step-time DELTA atomics) and cur[g] in one pass.
// Decode math identical to combine_kernel.
// ---------------------------------------------------------------------------
__global__ void combine_from_repl_kernel(const float* __restrict__ betas,
                                         const unsigned long long* __restrict__ repl,
                                         unsigned long long* __restrict__ buf,
                                         float* __restrict__ cur, int ntot) {
    int g = blockIdx.x * blockDim.x + threadIdx.x;
    if (g >= ntot) return;
    unsigned long long v = 0;
#pragma unroll
    for (int x = 0; x < NXCD; ++x)
        v += __builtin_nontemporal_load(&repl[(size_t)x * GT + g]);
    buf[g] = v;
    float people = (float)(v >> 51);
    float p = fminf(1.0f / (people - 1.0f), 1.0f);
    float beta = (g < GH) ? betas[0] : (g < GH + GC) ? betas[1] : betas[2];
    float sum = (float)((double)(long long)(v & SMASK) * INVFIX);
    cur[g] = (beta * p) * sum;
}

// ---------------------------------------------------------------------------
// combine: decode count + sum -> cur[g], float tree identical to reference.
// ---------------------------------------------------------------------------
__global__ void combine_kernel(const float* __restrict__ betas,
                               const unsigned long long* __restrict__ buf,
                               float* __restrict__ cur, int ntot) {
    int g = blockIdx.x * blockDim.x + threadIdx.x;
    if (g >= ntot) return;
    unsigned long long v = __builtin_nontemporal_load(&buf[g]);
    float people = (float)(v >> 51);
    float p = fminf(1.0f / (people - 1.0f), 1.0f);
    float beta = (g < GH) ? betas[0] : (g < GH + GC) ? betas[1] : betas[2];
    float sum = (float)((double)(long long)(v & SMASK) * INVFIX);
    cur[g] = (beta * p) * sum;
}

// ---------------------------------------------------------------------------
// step: one thread per agent; 8B packed state, three L2-resident gathers,
// gumbel-softmax hard Bernoulli decision, sparse DELTA scatter on infection.
// Verified math -- unchanged.
// ---------------------------------------------------------------------------
template <bool LAST>
__global__ void step_packed_kernel(const float* __restrict__ gum_t,  // + 2*t*n
                                   unsigned long long* __restrict__ packed,
                                   const float* __restrict__ cur,
                                   unsigned long long* __restrict__ buf,
                                   float* __restrict__ out_t,        // + t*n
                                   int n) {
    int i = blockIdx.x * blockDim.x + threadIdx.x;
    if (i >= n) return;

    unsigned long long w = __builtin_nontemporal_load(&packed[i]);
    float ninf = 0.0f;
    if (w & SUSCBIT) {
        int a = (int)(w & 0xFFFFFULL);
        int b = GH + (int)((w >> 20) & 0x7FFFULL);
        int c = GH + GC + (int)((w >> 35) & 0x1FFFFULL);
        // trans_susc, reference add order (susc == 1.0 exactly):
        float ts = cur[a];
        ts += cur[b];
        ts += cur[c];

        float ni = expf(-ts);                    // not_infected
        float l0 = logf(fmaxf(ni, 1e-15f));
        float l1 = logf(fmaxf(1.0f - ni, 1e-15f));
        float g0 = __builtin_nontemporal_load(&gum_t[i]);
        float g1 = __builtin_nontemporal_load(&gum_t[(size_t)n + i]);
        float z0 = (l0 + g0) / 0.1f;             // TAU = 0.1
        float z1 = (l1 + g1) / 0.1f;
        if (z1 > z0) {                           // argmax tie -> class 0
            ninf = 1.0f;
            if (!LAST) {
                packed[i] = w & ~SUSCBIT;        // owner-exclusive 8B store
                atomicAdd(&buf[a], DELTA);
                atomicAdd(&buf[b], DELTA);
                atomicAdd(&buf[c], DELTA);
            }
        }
    }
    __builtin_nontemporal_store(ninf, &out_t[i]);
}

// ---------------------------------------------------------------------------
// Fallback init (round-2 verified): device-scope atomics straight into buf.
// ---------------------------------------------------------------------------
__global__ void init_pack_kernel(const float* __restrict__ transm_in,
                                 const float* __restrict__ susc_in,
                                 const int* __restrict__ gh,
                                 const int* __restrict__ gc,
                                 const int* __restrict__ gs,
                                 unsigned long long* __restrict__ buf,
                                 unsigned long long* __restrict__ packed,
                                 int n) {
    int i = blockIdx.x * blockDim.x + threadIdx.x;
    if (i >= n) return;
    int a = __builtin_nontemporal_load(&gh[i]);
    int b = __builtin_nontemporal_load(&gc[i]);
    int c = __builtin_nontemporal_load(&gs[i]);
    float sv = __builtin_nontemporal_load(&susc_in[i]);
    float tv = __builtin_nontemporal_load(&transm_in[i]);

    unsigned long long w = (unsigned long long)(unsigned)a
                         | ((unsigned long long)(unsigned)b << 20)
                         | ((unsigned long long)(unsigned)c << 35)
                         | (sv != 0.0f ? SUSCBIT : 0ULL);
    __builtin_nontemporal_store(w, &packed[i]);

    unsigned long long e =
        (unsigned long long)((double)tv * FIXD + 0.5) + CUNIT;
    atomicAdd(&buf[a], e);
    atomicAdd(&buf[GH + b], e);
    atomicAdd(&buf[GH + GC + c], e);
}

extern "C" void kernel_launch(void* const* d_in, const int* in_sizes, int n_in,
                              void* d_out, int out_size, void* d_ws, size_t ws_size,
                              hipStream_t stream) {
    const float* betas     = (const float*)d_in[0];
    const float* transm_in = (const float*)d_in[1];
    float*       susc      = (float*)d_in[2];
    const float* gumbel    = (const float*)d_in[3];
    const int*   gh        = (const int*)d_in[4];
    const int*   gc        = (const int*)d_in[5];
    const int*   gs        = (const int*)d_in[6];
    int          n         = in_sizes[1];         // 2,000,000
    float*       out       = (float*)d_out;

    // Workspace layout:
    //   [buf: GT*8][cur: GT*4][packed: n*8][repl: 8*GT*8]
    unsigned long long* buf = (unsigned long long*)d_ws;
    float* cur = (float*)((char*)d_ws + (size_t)GT * 8);
    size_t packOff = ((size_t)GT * 12 + 255) & ~(size_t)255;
    unsigned long long* packed =
        (unsigned long long*)((char*)d_ws + packOff);
    size_t replOff = (packOff + (size_t)n * 8 + 255) & ~(size_t)255;
    unsigned long long* repl =
        (unsigned long long*)((char*)d_ws + replOff);
    size_t need_repl = replOff + (size_t)NXCD * GT * 8;
    size_t need_pack = packOff + (size_t)n * 8;

    const int blk = 256;
    const int grid_n = (n + blk - 1) / blk;
    const int grid_g = (GT + blk - 1) / blk;

    if (ws_size >= need_repl) {
        // ---- XCD-replicated init path ----
        hipMemsetAsync(repl, 0, (size_t)NXCD * GT * 8, stream);
        init_pack_repl_kernel<<<grid_n, blk, 0, stream>>>(
            transm_in, susc, gh, gc, gs, repl, packed, n);
        for (int t = 0; t < TSTEPS; ++t) {
            const float* gum_t = gumbel + (size_t)2 * t * n;
            float* out_t = out + (size_t)t * n;
            if (t == 0) {
                combine_from_repl_kernel<<<grid_g, blk, 0, stream>>>(
                    betas, repl, buf, cur, GT);
            } else {
                combine_kernel<<<grid_g, blk, 0, stream>>>(betas, buf, cur, GT);
            }
            if (t == TSTEPS - 1) {
                step_packed_kernel<true><<<grid_n, blk, 0, stream>>>(
                    gum_t, packed, cur, buf, out_t, n);
            } else {
                step_packed_kernel<false><<<grid_n, blk, 0, stream>>>(
                    gum_t, packed, cur, buf, out_t, n);
            }
        }
        return;
    }

    // ---- fallback: round-2 verified packed path ----
    hipMemsetAsync(buf, 0, (size_t)GT * 8, stream);
    if (ws_size >= need_pack) {
        init_pack_kernel<<<grid_n, blk, 0, stream>>>(
            transm_in, susc, gh, gc, gs, buf, packed, n);
        for (int t = 0; t < TSTEPS; ++t) {
            const float* gum_t = gumbel + (size_t)2 * t * n;
            float* out_t = out + (size_t)t * n;
            combine_kernel<<<grid_g, blk, 0, stream>>>(betas, buf, cur, GT);
            if (t == TSTEPS - 1) {
                step_packed_kernel<true><<<grid_n, blk, 0, stream>>>(
                    gum_t, packed, cur, buf, out_t, n);
            } else {
                step_packed_kernel<false><<<grid_n, blk, 0, stream>>>(
                    gum_t, packed, cur, buf, out_t, n);
            }
        }
    }
}

// Round 4
// 904.441 us; speedup vs baseline: 1.0881x; 1.0881x over previous
//
#include <hip/hip_runtime.h>

typedef unsigned long long u64;

// Problem constants (fixed by the reference file).
#define NAGENTS 2000000
#define GH 800000
#define GC 20000
#define GS 65000
#define GT (GH + GC + GS)   // 885000 total groups
#define TSTEPS 10

// Fixed-point group-sum encoding, one uint64 per group:
//   bits [0,51)  : sum of round(transm * 2^44)   (exact; order-free)
//   bits [51,64) : member count
// Proven numerics -- do not touch.
#define FIXD   17592186044416.0          // 2^44
#define INVFIX (1.0 / 17592186044416.0)  // 2^-44
#define DELTA  3518437208883ULL          // round(0.2 * 2^44)
#define CUNIT  (1ULL << 51)
#define SMASK  (CUNIT - 1ULL)

// Packed per-agent state, one uint64:
//   bits [0,20): gh  bits [20,35): gc  bits [35,52): gs  bit 63: susceptible
#define SUSCBIT (1ULL << 63)

// ---------------------------------------------------------------------------
// Atomic-free init: edge-balanced bins.
//   household: 256 gids/bin (~640 edges), company: 8 gids/bin (~800 edges),
//   school: 32 gids/bin (~985 edges).  800000/256=3125, 20000/8=2500,
//   ceil(65000/32)=2032 (last bin spans 8 gids).
// ---------------------------------------------------------------------------
#define NB_H 3125
#define NB_C 2500
#define NB_S 2032
#define NBINS (NB_H + NB_C + NB_S)   // 7657
#define NBP 256                      // partition blocks for P1/P2
#define P12_THR 512
#define SCAN_ELEMS 2048

__device__ __forceinline__ int bin_h(int a) { return a >> 8; }
__device__ __forceinline__ int bin_c(int c) { return NB_H + (c >> 3); }
__device__ __forceinline__ int bin_s(int s) { return NB_H + NB_C + (s >> 5); }

// P1: per-block LDS histogram over bins + build packed[] in the same pass.
__global__ __launch_bounds__(P12_THR) void p1_hist_pack(
    const int* __restrict__ gh, const int* __restrict__ gc,
    const int* __restrict__ gs, const float* __restrict__ susc_in,
    u64* __restrict__ packed, unsigned* __restrict__ hist,
    int n, int apb) {
    __shared__ unsigned h[NBINS];
    for (int j = threadIdx.x; j < NBINS; j += P12_THR) h[j] = 0;
    __syncthreads();
    const int b = blockIdx.x;
    const int lo = b * apb, hi = min(n, lo + apb);
    for (int i = lo + threadIdx.x; i < hi; i += P12_THR) {
        int a = gh[i], c = gc[i], s = gs[i];
        float sv = susc_in[i];
        u64 w = (u64)(unsigned)a | ((u64)(unsigned)c << 20)
              | ((u64)(unsigned)s << 35) | (sv != 0.0f ? SUSCBIT : 0ULL);
        __builtin_nontemporal_store(w, &packed[i]);
        atomicAdd(&h[bin_h(a)], 1u);
        atomicAdd(&h[bin_c(c)], 1u);
        atomicAdd(&h[bin_s(s)], 1u);
    }
    __syncthreads();
    for (int j = threadIdx.x; j < NBINS; j += P12_THR)
        hist[(size_t)j * NBP + b] = h[j];
}

// S1: exclusive scan of 2048 elems/block (in place) + block totals.
__global__ __launch_bounds__(1024) void s1_scan(unsigned* __restrict__ data,
                                                unsigned* __restrict__ sums,
                                                int ntot) {
    __shared__ unsigned sA[1024], sB[1024];
    const int base = blockIdx.x * SCAN_ELEMS;
    const int t = threadIdx.x;
    unsigned v0 = (base + 2 * t     < ntot) ? data[base + 2 * t]     : 0u;
    unsigned v1 = (base + 2 * t + 1 < ntot) ? data[base + 2 * t + 1] : 0u;
    sA[t] = v0 + v1;
    __syncthreads();
    unsigned* src = sA; unsigned* dst = sB;
    for (int off = 1; off < 1024; off <<= 1) {
        dst[t] = src[t] + (t >= off ? src[t - off] : 0u);
        __syncthreads();
        unsigned* tmp = src; src = dst; dst = tmp;
    }
    unsigned incl = src[t];
    unsigned expair = incl - (v0 + v1);
    if (base + 2 * t     < ntot) data[base + 2 * t]     = expair;
    if (base + 2 * t + 1 < ntot) data[base + 2 * t + 1] = expair + v0;
    if (t == 1023) sums[blockIdx.x] = incl;   // block total
}

// S3: add scanned block bases back.
__global__ __launch_bounds__(1024) void s3_add(unsigned* __restrict__ data,
                                               const unsigned* __restrict__ exsums,
                                               int ntot) {
    unsigned base = exsums[blockIdx.x];
    for (int k = 0; k < 2; ++k) {
        int j = blockIdx.x * SCAN_ELEMS + k * 1024 + threadIdx.x;
        if (j < ntot) data[j] += base;
    }
}

// P2: replay P1's traversal; LDS cursors = scanned offsets; write (gid,transm).
__global__ __launch_bounds__(P12_THR) void p2_scatter(
    const int* __restrict__ gh, const int* __restrict__ gc,
    const int* __restrict__ gs, const float* __restrict__ transm,
    const unsigned* __restrict__ offs, u64* __restrict__ binned,
    int n, int apb) {
    __shared__ unsigned cur[NBINS];
    const int b = blockIdx.x;
    for (int j = threadIdx.x; j < NBINS; j += P12_THR)
        cur[j] = offs[(size_t)j * NBP + b];
    __syncthreads();
    const int lo = b * apb, hi = min(n, lo + apb);
    for (int i = lo + threadIdx.x; i < hi; i += P12_THR) {
        int a = gh[i], c = gc[i], s = gs[i];
        unsigned fb = __float_as_uint(transm[i]);
        unsigned r0 = atomicAdd(&cur[bin_h(a)], 1u);
        binned[r0] = ((u64)(unsigned)a << 32) | fb;
        unsigned r1 = atomicAdd(&cur[bin_c(c)], 1u);
        binned[r1] = ((u64)(unsigned)(GH + c) << 32) | fb;
        unsigned r2 = atomicAdd(&cur[bin_s(s)], 1u);
        binned[r2] = ((u64)(unsigned)(GH + GC + s) << 32) | fb;
    }
}

// P3: one block per bin; contiguous edge run -> LDS u64 accum -> buf.
__global__ __launch_bounds__(256) void p3_reduce(
    const unsigned* __restrict__ offs, const u64* __restrict__ binned,
    u64* __restrict__ buf, int etotal) {
    __shared__ u64 acc[256];
    const int bin = blockIdx.x;
    int gidbase, span;
    if (bin < NB_H)               { gidbase = bin << 8;                      span = 256; }
    else if (bin < NB_H + NB_C)   { gidbase = GH + ((bin - NB_H) << 3);      span = 8; }
    else { gidbase = GH + GC + ((bin - NB_H - NB_C) << 5); span = min(32, GT - gidbase); }
    for (int j = threadIdx.x; j < span; j += 256) acc[j] = 0ULL;
    __syncthreads();
    unsigned start = offs[(size_t)bin * NBP];
    unsigned end = (bin == NBINS - 1) ? (unsigned)etotal
                                      : offs[(size_t)(bin + 1) * NBP];
    for (unsigned e = start + threadIdx.x; e < end; e += 256) {
        u64 kv = binned[e];
        int gid = (int)(kv >> 32);
        float tv = __uint_as_float((unsigned)kv);
        u64 ev = (u64)((double)tv * FIXD + 0.5) + CUNIT;   // exact, order-free
        atomicAdd(&acc[gid - gidbase], ev);                // LDS atomic
    }
    __syncthreads();
    for (int j = threadIdx.x; j < span; j += 256)
        buf[gidbase + j] = acc[j];
}

// ---------------------------------------------------------------------------
// combine: decode count + sum -> cur[g], float tree identical to reference.
// ---------------------------------------------------------------------------
__global__ void combine_kernel(const float* __restrict__ betas,
                               const u64* __restrict__ buf,
                               float* __restrict__ cur, int ntot) {
    int g = blockIdx.x * blockDim.x + threadIdx.x;
    if (g >= ntot) return;
    u64 v = __builtin_nontemporal_load(&buf[g]);
    float people = (float)(v >> 51);
    float p = fminf(1.0f / (people - 1.0f), 1.0f);
    float beta = (g < GH) ? betas[0] : (g < GH + GC) ? betas[1] : betas[2];
    float sum = (float)((double)(long long)(v & SMASK) * INVFIX);
    cur[g] = (beta * p) * sum;
}

// ---------------------------------------------------------------------------
// step: verified math -- unchanged.
// ---------------------------------------------------------------------------
template <bool LAST>
__global__ void step_packed_kernel(const float* __restrict__ gum_t,  // + 2*t*n
                                   u64* __restrict__ packed,
                                   const float* __restrict__ cur,
                                   u64* __restrict__ buf,
                                   float* __restrict__ out_t,        // + t*n
                                   int n) {
    int i = blockIdx.x * blockDim.x + threadIdx.x;
    if (i >= n) return;

    u64 w = __builtin_nontemporal_load(&packed[i]);
    float ninf = 0.0f;
    if (w & SUSCBIT) {
        int a = (int)(w & 0xFFFFFULL);
        int b = GH + (int)((w >> 20) & 0x7FFFULL);
        int c = GH + GC + (int)((w >> 35) & 0x1FFFFULL);
        float ts = cur[a];
        ts += cur[b];
        ts += cur[c];

        float ni = expf(-ts);                    // not_infected
        float l0 = logf(fmaxf(ni, 1e-15f));
        float l1 = logf(fmaxf(1.0f - ni, 1e-15f));
        float g0 = __builtin_nontemporal_load(&gum_t[i]);
        float g1 = __builtin_nontemporal_load(&gum_t[(size_t)n + i]);
        float z0 = (l0 + g0) / 0.1f;             // TAU = 0.1
        float z1 = (l1 + g1) / 0.1f;
        if (z1 > z0) {                           // argmax tie -> class 0
            ninf = 1.0f;
            if (!LAST) {
                packed[i] = w & ~SUSCBIT;
                atomicAdd(&buf[a], DELTA);
                atomicAdd(&buf[b], DELTA);
                atomicAdd(&buf[c], DELTA);
            }
        }
    }
    __builtin_nontemporal_store(ninf, &out_t[i]);
}

// ---------------------------------------------------------------------------
// Fallback init (round-2 verified): device-scope atomics straight into buf.
// ---------------------------------------------------------------------------
__global__ void init_pack_kernel(const float* __restrict__ transm_in,
                                 const float* __restrict__ susc_in,
                                 const int* __restrict__ gh,
                                 const int* __restrict__ gc,
                                 const int* __restrict__ gs,
                                 u64* __restrict__ buf,
                                 u64* __restrict__ packed,
                                 int n) {
    int i = blockIdx.x * blockDim.x + threadIdx.x;
    if (i >= n) return;
    int a = gh[i], b = gc[i], c = gs[i];
    float sv = susc_in[i];
    float tv = transm_in[i];
    u64 w = (u64)(unsigned)a | ((u64)(unsigned)b << 20)
          | ((u64)(unsigned)c << 35) | (sv != 0.0f ? SUSCBIT : 0ULL);
    __builtin_nontemporal_store(w, &packed[i]);
    u64 e = (u64)((double)tv * FIXD + 0.5) + CUNIT;
    atomicAdd(&buf[a], e);
    atomicAdd(&buf[GH + b], e);
    atomicAdd(&buf[GH + GC + c], e);
}

extern "C" void kernel_launch(void* const* d_in, const int* in_sizes, int n_in,
                              void* d_out, int out_size, void* d_ws, size_t ws_size,
                              hipStream_t stream) {
    const float* betas     = (const float*)d_in[0];
    const float* transm_in = (const float*)d_in[1];
    float*       susc      = (float*)d_in[2];
    const float* gumbel    = (const float*)d_in[3];
    const int*   gh        = (const int*)d_in[4];
    const int*   gc        = (const int*)d_in[5];
    const int*   gs        = (const int*)d_in[6];
    int          n         = in_sizes[1];         // 2,000,000
    float*       out       = (float*)d_out;

    // Workspace layout:
    //  [buf GT*8][cur GT*4][packed n*8][binned 3n*8][hist NBINS*NBP*4][sums 4KB]
    char* base = (char*)d_ws;
    u64*   buf    = (u64*)base;
    float* cur    = (float*)(base + (size_t)GT * 8);
    size_t packOff = ((size_t)GT * 12 + 255) & ~(size_t)255;
    u64*   packed = (u64*)(base + packOff);
    size_t binOff  = (packOff + (size_t)n * 8 + 255) & ~(size_t)255;
    u64*   binned = (u64*)(base + binOff);
    size_t histOff = (binOff + (size_t)3 * n * 8 + 255) & ~(size_t)255;
    unsigned* hist = (unsigned*)(base + histOff);
    size_t sumsOff = (histOff + (size_t)NBINS * NBP * 4 + 255) & ~(size_t)255;
    unsigned* sums = (unsigned*)(base + sumsOff);
    size_t need_sort = sumsOff + 4096;
    size_t need_pack = packOff + (size_t)n * 8;

    const int blk = 256;
    const int grid_n = (n + blk - 1) / blk;
    const int grid_g = (GT + blk - 1) / blk;

    if (ws_size >= need_sort) {
        // ---- atomic-free init ----
        const int apb = (n + NBP - 1) / NBP;
        const int nscan = NBINS * NBP;                       // 1,960,192
        const int nS1 = (nscan + SCAN_ELEMS - 1) / SCAN_ELEMS;  // 958

        p1_hist_pack<<<NBP, P12_THR, 0, stream>>>(gh, gc, gs, susc,
                                                  packed, hist, n, apb);
        s1_scan<<<nS1, 1024, 0, stream>>>(hist, sums, nscan);
        s1_scan<<<1, 1024, 0, stream>>>(sums, &sums[1023], nS1); // scan totals
        s3_add<<<nS1, 1024, 0, stream>>>(hist, sums, nscan);
        p2_scatter<<<NBP, P12_THR, 0, stream>>>(gh, gc, gs, transm_in,
                                                hist, binned, n, apb);
        p3_reduce<<<NBINS, 256, 0, stream>>>(hist, binned, buf, 3 * n);

        for (int t = 0; t < TSTEPS; ++t) {
            const float* gum_t = gumbel + (size_t)2 * t * n;
            float* out_t = out + (size_t)t * n;
            combine_kernel<<<grid_g, blk, 0, stream>>>(betas, buf, cur, GT);
            if (t == TSTEPS - 1) {
                step_packed_kernel<true><<<grid_n, blk, 0, stream>>>(
                    gum_t, packed, cur, buf, out_t, n);
            } else {
                step_packed_kernel<false><<<grid_n, blk, 0, stream>>>(
                    gum_t, packed, cur, buf, out_t, n);
            }
        }
        return;
    }

    // ---- fallback: round-2 verified packed path ----
    hipMemsetAsync(buf, 0, (size_t)GT * 8, stream);
    if (ws_size >= need_pack) {
        init_pack_kernel<<<grid_n, blk, 0, stream>>>(
            transm_in, susc, gh, gc, gs, buf, packed, n);
        for (int t = 0; t < TSTEPS; ++t) {
            const float* gum_t = gumbel + (size_t)2 * t * n;
            float* out_t = out + (size_t)t * n;
            combine_kernel<<<grid_g, blk, 0, stream>>>(betas, buf, cur, GT);
            if (t == TSTEPS - 1) {
                step_packed_kernel<true><<<grid_n, blk, 0, stream>>>(
                    gum_t, packed, cur, buf, out_t, n);
            } else {
                step_packed_kernel<false><<<grid_n, blk, 0, stream>>>(
                    gum_t, packed, cur, buf, out_t, n);
            }
        }
    }
}

// Round 7
// 826.879 us; speedup vs baseline: 1.1902x; 1.0938x over previous
//
#include <hip/hip_runtime.h>

typedef unsigned long long u64;

// Problem constants (fixed by the reference file).
#define NAGENTS 2000000
#define GH 800000
#define GC 20000
#define GS 65000
#define GT (GH + GC + GS)   // 885000 total groups
#define TSTEPS 10

// Fixed-point group-sum encoding, one uint64 per group:
//   bits [0,51)  : sum of round(transm * 2^44)   (exact; order-free)
//   bits [51,64) : member count
// Proven numerics -- do not touch.
#define FIXD   17592186044416.0          // 2^44
#define INVFIX (1.0 / 17592186044416.0)  // 2^-44
#define DELTA  3518437208883ULL          // round(0.2 * 2^44)
#define CUNIT  (1ULL << 51)
#define SMASK  (CUNIT - 1ULL)

// Packed per-agent state, one uint64:
//   bits [0,20): gh  bits [20,35): gc  bits [35,52): gs  bit 63: susceptible
#define SUSCBIT (1ULL << 63)

// ---------------------------------------------------------------------------
// Atomic-free init, COARSE bins (round-4 fix: long runs, small open-line set).
//   household: 2048 gids/bin -> 391 bins (~5120 edges/bin)
//   company  :   64 gids/bin -> 313 bins (~6400 edges/bin)
//   school   :  256 gids/bin -> 254 bins (~7900 edges/bin)
// Per-(bin,block) run ~20-31 edges (160-248B) -> write lines complete in L2.
// ---------------------------------------------------------------------------
#define NB_H 391
#define NB_C 313
#define NB_S 254
#define NBINS (NB_H + NB_C + NB_S)   // 958
#define NBP 256                      // partition blocks for P1/P2
#define P12_THR 512
#define SCAN_ELEMS 2048

__device__ __forceinline__ int bin_h(int a) { return a >> 11; }
__device__ __forceinline__ int bin_c(int c) { return NB_H + (c >> 6); }
__device__ __forceinline__ int bin_s(int s) { return NB_H + NB_C + (s >> 8); }

// P1: per-block LDS histogram over bins + build packed[] in the same pass.
__global__ __launch_bounds__(P12_THR) void p1_hist_pack(
    const int* __restrict__ gh, const int* __restrict__ gc,
    const int* __restrict__ gs, const float* __restrict__ susc_in,
    u64* __restrict__ packed, unsigned* __restrict__ hist,
    int n, int apb) {
    __shared__ unsigned h[NBINS];
    for (int j = threadIdx.x; j < NBINS; j += P12_THR) h[j] = 0;
    __syncthreads();
    const int b = blockIdx.x;
    const int lo = b * apb, hi = min(n, lo + apb);
    for (int i = lo + threadIdx.x; i < hi; i += P12_THR) {
        int a = gh[i], c = gc[i], s = gs[i];
        float sv = susc_in[i];
        u64 w = (u64)(unsigned)a | ((u64)(unsigned)c << 20)
              | ((u64)(unsigned)s << 35) | (sv != 0.0f ? SUSCBIT : 0ULL);
        __builtin_nontemporal_store(w, &packed[i]);
        atomicAdd(&h[bin_h(a)], 1u);
        atomicAdd(&h[bin_c(c)], 1u);
        atomicAdd(&h[bin_s(s)], 1u);
    }
    __syncthreads();
    for (int j = threadIdx.x; j < NBINS; j += P12_THR)
        hist[(size_t)j * NBP + b] = h[j];
}

// S1: exclusive scan of 2048 elems/block (in place) + block totals.
__global__ __launch_bounds__(1024) void s1_scan(unsigned* __restrict__ data,
                                                unsigned* __restrict__ sums,
                                                int ntot) {
    __shared__ unsigned sA[1024], sB[1024];
    const int base = blockIdx.x * SCAN_ELEMS;
    const int t = threadIdx.x;
    unsigned v0 = (base + 2 * t     < ntot) ? data[base + 2 * t]     : 0u;
    unsigned v1 = (base + 2 * t + 1 < ntot) ? data[base + 2 * t + 1] : 0u;
    sA[t] = v0 + v1;
    __syncthreads();
    unsigned* src = sA; unsigned* dst = sB;
    for (int off = 1; off < 1024; off <<= 1) {
        dst[t] = src[t] + (t >= off ? src[t - off] : 0u);
        __syncthreads();
        unsigned* tmp = src; src = dst; dst = tmp;
    }
    unsigned incl = src[t];
    unsigned expair = incl - (v0 + v1);
    if (base + 2 * t     < ntot) data[base + 2 * t]     = expair;
    if (base + 2 * t + 1 < ntot) data[base + 2 * t + 1] = expair + v0;
    if (t == 1023) sums[blockIdx.x] = incl;   // block total
}

// S3: add scanned block bases back.
__global__ __launch_bounds__(1024) void s3_add(unsigned* __restrict__ data,
                                               const unsigned* __restrict__ exsums,
                                               int ntot) {
    unsigned base = exsums[blockIdx.x];
    for (int k = 0; k < 2; ++k) {
        int j = blockIdx.x * SCAN_ELEMS + k * 1024 + threadIdx.x;
        if (j < ntot) data[j] += base;
    }
}

// P2: replay P1's traversal; LDS cursors = scanned offsets; write (gid,transm).
__global__ __launch_bounds__(P12_THR) void p2_scatter(
    const int* __restrict__ gh, const int* __restrict__ gc,
    const int* __restrict__ gs, const float* __restrict__ transm,
    const unsigned* __restrict__ offs, u64* __restrict__ binned,
    int n, int apb) {
    __shared__ unsigned cur[NBINS];
    const int b = blockIdx.x;
    for (int j = threadIdx.x; j < NBINS; j += P12_THR)
        cur[j] = offs[(size_t)j * NBP + b];
    __syncthreads();
    const int lo = b * apb, hi = min(n, lo + apb);
    for (int i = lo + threadIdx.x; i < hi; i += P12_THR) {
        int a = gh[i], c = gc[i], s = gs[i];
        unsigned fb = __float_as_uint(transm[i]);
        unsigned r0 = atomicAdd(&cur[bin_h(a)], 1u);
        binned[r0] = ((u64)(unsigned)a << 32) | fb;
        unsigned r1 = atomicAdd(&cur[bin_c(c)], 1u);
        binned[r1] = ((u64)(unsigned)(GH + c) << 32) | fb;
        unsigned r2 = atomicAdd(&cur[bin_s(s)], 1u);
        binned[r2] = ((u64)(unsigned)(GH + GC + s) << 32) | fb;
    }
}

// P3: one block per bin; contiguous edge run -> LDS u64 accum -> buf.
__global__ __launch_bounds__(256) void p3_reduce(
    const unsigned* __restrict__ offs, const u64* __restrict__ binned,
    u64* __restrict__ buf, int etotal) {
    __shared__ u64 acc[2048];
    const int bin = blockIdx.x;
    int gidbase, span;
    if (bin < NB_H) {
        gidbase = bin << 11;                     span = min(2048, GH - gidbase);
    } else if (bin < NB_H + NB_C) {
        gidbase = GH + ((bin - NB_H) << 6);      span = min(64, GH + GC - gidbase);
    } else {
        gidbase = GH + GC + ((bin - NB_H - NB_C) << 8);
        span = min(256, GT - gidbase);
    }
    for (int j = threadIdx.x; j < span; j += 256) acc[j] = 0ULL;
    __syncthreads();
    unsigned start = offs[(size_t)bin * NBP];
    unsigned end = (bin == NBINS - 1) ? (unsigned)etotal
                                      : offs[(size_t)(bin + 1) * NBP];
    for (unsigned e = start + threadIdx.x; e < end; e += 256) {
        u64 kv = __builtin_nontemporal_load(&binned[e]);
        int gid = (int)(kv >> 32);
        float tv = __uint_as_float((unsigned)kv);
        u64 ev = (u64)((double)tv * FIXD + 0.5) + CUNIT;   // exact, order-free
        atomicAdd(&acc[gid - gidbase], ev);                // LDS atomic
    }
    __syncthreads();
    for (int j = threadIdx.x; j < span; j += 256)
        buf[gidbase + j] = acc[j];
}

// ---------------------------------------------------------------------------
// combine: decode count + sum -> cur[g], float tree identical to reference.
// ---------------------------------------------------------------------------
__global__ void combine_kernel(const float* __restrict__ betas,
                               const u64* __restrict__ buf,
                               float* __restrict__ cur, int ntot) {
    int g = blockIdx.x * blockDim.x + threadIdx.x;
    if (g >= ntot) return;
    u64 v = __builtin_nontemporal_load(&buf[g]);
    float people = (float)(v >> 51);
    float p = fminf(1.0f / (people - 1.0f), 1.0f);
    float beta = (g < GH) ? betas[0] : (g < GH + GC) ? betas[1] : betas[2];
    float sum = (float)((double)(long long)(v & SMASK) * INVFIX);
    cur[g] = (beta * p) * sum;
}

// ---------------------------------------------------------------------------
// step: verified math -- unchanged.
// ---------------------------------------------------------------------------
template <bool LAST>
__global__ __launch_bounds__(256) void step_packed_kernel(
                                   const float* __restrict__ gum_t,  // + 2*t*n
                                   u64* __restrict__ packed,
                                   const float* __restrict__ cur,
                                   u64* __restrict__ buf,
                                   float* __restrict__ out_t,        // + t*n
                                   int n) {
    int i = blockIdx.x * blockDim.x + threadIdx.x;
    if (i >= n) return;

    u64 w = __builtin_nontemporal_load(&packed[i]);
    float ninf = 0.0f;
    if (w & SUSCBIT) {
        int a = (int)(w & 0xFFFFFULL);
        int b = GH + (int)((w >> 20) & 0x7FFFULL);
        int c = GH + GC + (int)((w >> 35) & 0x1FFFFULL);
        float ts = cur[a];
        ts += cur[b];
        ts += cur[c];

        float ni = expf(-ts);                    // not_infected
        float l0 = logf(fmaxf(ni, 1e-15f));
        float l1 = logf(fmaxf(1.0f - ni, 1e-15f));
        float g0 = __builtin_nontemporal_load(&gum_t[i]);
        float g1 = __builtin_nontemporal_load(&gum_t[(size_t)n + i]);
        float z0 = (l0 + g0) / 0.1f;             // TAU = 0.1
        float z1 = (l1 + g1) / 0.1f;
        if (z1 > z0) {                           // argmax tie -> class 0
            ninf = 1.0f;
            if (!LAST) {
                packed[i] = w & ~SUSCBIT;
                atomicAdd(&buf[a], DELTA);
                atomicAdd(&buf[b], DELTA);
                atomicAdd(&buf[c], DELTA);
            }
        }
    }
    __builtin_nontemporal_store(ninf, &out_t[i]);
}

// ---------------------------------------------------------------------------
// Fallback init (round-2 verified): device-scope atomics straight into buf.
// ---------------------------------------------------------------------------
__global__ void init_pack_kernel(const float* __restrict__ transm_in,
                                 const float* __restrict__ susc_in,
                                 const int* __restrict__ gh,
                                 const int* __restrict__ gc,
                                 const int* __restrict__ gs,
                                 u64* __restrict__ buf,
                                 u64* __restrict__ packed,
                                 int n) {
    int i = blockIdx.x * blockDim.x + threadIdx.x;
    if (i >= n) return;
    int a = gh[i], b = gc[i], c = gs[i];
    float sv = susc_in[i];
    float tv = transm_in[i];
    u64 w = (u64)(unsigned)a | ((u64)(unsigned)b << 20)
          | ((u64)(unsigned)c << 35) | (sv != 0.0f ? SUSCBIT : 0ULL);
    __builtin_nontemporal_store(w, &packed[i]);
    u64 e = (u64)((double)tv * FIXD + 0.5) + CUNIT;
    atomicAdd(&buf[a], e);
    atomicAdd(&buf[GH + b], e);
    atomicAdd(&buf[GH + GC + c], e);
}

extern "C" void kernel_launch(void* const* d_in, const int* in_sizes, int n_in,
                              void* d_out, int out_size, void* d_ws, size_t ws_size,
                              hipStream_t stream) {
    const float* betas     = (const float*)d_in[0];
    const float* transm_in = (const float*)d_in[1];
    float*       susc      = (float*)d_in[2];
    const float* gumbel    = (const float*)d_in[3];
    const int*   gh        = (const int*)d_in[4];
    const int*   gc        = (const int*)d_in[5];
    const int*   gs        = (const int*)d_in[6];
    int          n         = in_sizes[1];         // 2,000,000
    float*       out       = (float*)d_out;

    // Workspace layout:
    //  [buf GT*8][cur GT*4][packed n*8][binned 3n*8][hist NBINS*NBP*4][sums 4KB]
    char* base = (char*)d_ws;
    u64*   buf    = (u64*)base;
    float* cur    = (float*)(base + (size_t)GT * 8);
    size_t packOff = ((size_t)GT * 12 + 255) & ~(size_t)255;
    u64*   packed = (u64*)(base + packOff);
    size_t binOff  = (packOff + (size_t)n * 8 + 255) & ~(size_t)255;
    u64*   binned = (u64*)(base + binOff);
    size_t histOff = (binOff + (size_t)3 * n * 8 + 255) & ~(size_t)255;
    unsigned* hist = (unsigned*)(base + histOff);
    size_t sumsOff = (histOff + (size_t)NBINS * NBP * 4 + 255) & ~(size_t)255;
    unsigned* sums = (unsigned*)(base + sumsOff);
    size_t need_sort = sumsOff + 4096;
    size_t need_pack = packOff + (size_t)n * 8;

    const int blk = 256;
    const int grid_n = (n + blk - 1) / blk;
    const int grid_g = (GT + blk - 1) / blk;

    if (ws_size >= need_sort) {
        // ---- atomic-free init ----
        const int apb = (n + NBP - 1) / NBP;
        const int nscan = NBINS * NBP;                          // 245,248
        const int nS1 = (nscan + SCAN_ELEMS - 1) / SCAN_ELEMS;  // 120

        p1_hist_pack<<<NBP, P12_THR, 0, stream>>>(gh, gc, gs, susc,
                                                  packed, hist, n, apb);
        s1_scan<<<nS1, 1024, 0, stream>>>(hist, sums, nscan);
        s1_scan<<<1, 1024, 0, stream>>>(sums, &sums[1023], nS1); // scan totals
        s3_add<<<nS1, 1024, 0, stream>>>(hist, sums, nscan);
        p2_scatter<<<NBP, P12_THR, 0, stream>>>(gh, gc, gs, transm_in,
                                                hist, binned, n, apb);
        p3_reduce<<<NBINS, 256, 0, stream>>>(hist, binned, buf, 3 * n);

        for (int t = 0; t < TSTEPS; ++t) {
            const float* gum_t = gumbel + (size_t)2 * t * n;
            float* out_t = out + (size_t)t * n;
            combine_kernel<<<grid_g, blk, 0, stream>>>(betas, buf, cur, GT);
            if (t == TSTEPS - 1) {
                step_packed_kernel<true><<<grid_n, blk, 0, stream>>>(
                    gum_t, packed, cur, buf, out_t, n);
            } else {
                step_packed_kernel<false><<<grid_n, blk, 0, stream>>>(
                    gum_t, packed, cur, buf, out_t, n);
            }
        }
        return;
    }

    // ---- fallback: round-2 verified packed path ----
    hipMemsetAsync(buf, 0, (size_t)GT * 8, stream);
    if (ws_size >= need_pack) {
        init_pack_kernel<<<grid_n, blk, 0, stream>>>(
            transm_in, susc, gh, gc, gs, buf, packed, n);
        for (int t = 0; t < TSTEPS; ++t) {
            const float* gum_t = gumbel + (size_t)2 * t * n;
            float* out_t = out + (size_t)t * n;
            combine_kernel<<<grid_g, blk, 0, stream>>>(betas, buf, cur, GT);
            if (t == TSTEPS - 1) {
                step_packed_kernel<true><<<grid_n, blk, 0, stream>>>(
                    gum_t, packed, cur, buf, out_t, n);
            } else {
                step_packed_kernel<false><<<grid_n, blk, 0, stream>>>(
                    gum_t, packed, cur, buf, out_t, n);
            }
        }
    }
}